// Round 5
// baseline (281.123 us; speedup 1.0000x reference)
//
#include <hip/hip_runtime.h>
#include <hip/hip_bf16.h>

// GCN 3-layer forward on gfx950.
// Established: inputs f32 (flags[0]=1) / edges int64 (flags[1]=1), device-
// detected; bf16 MFMA GEMM (operand-swapped 16x16x32); zero-global-atomic
// CSR build. Rounds 1-4 lesson: ALL CSR variants cost 271-278us total ->
// CSR is second-order; NHB=256 (full-chip, 1 blk/CU) measured best -> revert
// to round-2 CSR exactly. This round's lever: aggregate gather is LATENCY-
// bound (2-deep unroll = only 8 edges in flight/wave; mean degree 16 needs 2
// dependent rounds). Deepened to 4-deep: all ~16 edges of a mean node issue
// their loads in ONE burst before any FMA. Traffic unchanged -> if this is
// flat, aggregate is at the L3 random-gather ceiling.

typedef float vf4 __attribute__((ext_vector_type(4)));
typedef unsigned vu4 __attribute__((ext_vector_type(4)));
typedef unsigned vu2 __attribute__((ext_vector_type(2)));
typedef short bf8v __attribute__((ext_vector_type(8)));
typedef float f4v __attribute__((ext_vector_type(4)));

constexpr int PCAP = 25000;  // packed (2-col) LDS histogram capacity -> N <= 50000
constexpr int NHB  = 256;    // histogram blocks (full chip); epb must stay < 2^16

__device__ __forceinline__ float bits2f(unsigned u) {
    union { unsigned u; float f; } c; c.u = u; return c.f;
}
__device__ __forceinline__ unsigned short f2bfu(float v) {
    __hip_bfloat16 h = __float2bfloat16(v);
    union { __hip_bfloat16 h; unsigned short u; } c; c.h = h; return c.u;
}
__device__ __forceinline__ float bflo(unsigned d) { return bits2f(d << 16); }
__device__ __forceinline__ float bfhi(unsigned d) { return bits2f(d & 0xffff0000u); }

__global__ void detect_dtypes(const void* __restrict__ x,
                              const void* __restrict__ ei,
                              int* __restrict__ flags) {
    const int t = threadIdx.x;
    const int lane = t & 63;
    if (t < 64) {
        const unsigned short* p = (const unsigned short*)x;
        int e = (p[2 * (lane * 16)] >> 7) & 0xFF;
        unsigned long long m = __ballot(e < 100 || e > 140);
        if (lane == 0) flags[0] = (__popcll(m) > 16) ? 1 : 0;
    } else if (t < 128) {
        const int* p = (const int*)ei;
        unsigned long long m = __ballot(p[2 * (lane * 16) + 1] != 0);
        if (lane == 0) flags[1] = (__popcll(m) < 2) ? 1 : 0;
    }
}

__device__ __forceinline__ int edge_at(const void* ei, long long idx, bool i64) {
    return i64 ? (int)((const long long*)ei)[idx] : ((const int*)ei)[idx];
}

// ---- histogram CSR build (no global atomics), round-2 proven config ----
// Pass 1: per-block LDS histogram of a contiguous edge chunk; edges converted
// to int32 on the way. Packed ushort pair per u32; per-block per-col count
// <= epb < 2^16 so the +1 / +(1<<16) LDS atomic can never carry.
__global__ __launch_bounds__(1024) void hist_count(const void* __restrict__ ei,
                                                   int* __restrict__ row32,
                                                   int* __restrict__ col32,
                                                   unsigned* __restrict__ histg,
                                                   const int* __restrict__ flags,
                                                   int e, int epb, int pc) {
    __shared__ unsigned h[PCAP];
    const int t = threadIdx.x;
    const int b = blockIdx.x;
    for (int j = t; j < pc; j += 1024) h[j] = 0u;
    __syncthreads();
    const bool i64 = flags[1] != 0;
    const int base = b * epb;
    const int end = min(e, base + epb);
    for (int i = base + t; i < end; i += 1024) {
        int r = edge_at(ei, i, i64);
        int c = edge_at(ei, (long long)e + i, i64);
        row32[i] = r;
        col32[i] = c;
        atomicAdd(&h[c >> 1], (c & 1) ? 0x10000u : 1u);
    }
    __syncthreads();
    unsigned* out = histg + (size_t)b * pc;
    for (int j = t; j < pc; j += 1024) __builtin_nontemporal_store(h[j], &out[j]);
}

// Pass 2: per packed column, exclusive prefix across the NHB block rows
// (packed u32 adds are carry-free: per-col totals = degree << 2^16), write
// bases back in place and emit per-col degree into cnt.
__global__ __launch_bounds__(256) void hist_scan(unsigned* __restrict__ histg,
                                                 int* __restrict__ cnt, int pc, int n) {
    __shared__ unsigned tile[NHB][65];
    const int t = threadIdx.x;
    const int c = t & 63;
    const int jc = blockIdx.x * 64 + c;
    for (int r = t >> 6; r < NHB; r += 4)
        tile[r][c] = (jc < pc) ? histg[(size_t)r * pc + jc] : 0u;
    __syncthreads();
    if (t < 64 && jc < pc) {
        unsigned run = 0;
        for (int r = 0; r < NHB; ++r) {
            unsigned v = tile[r][t];
            tile[r][t] = run;
            run += v;
        }
        int c0 = jc * 2;
        if (c0 < n) cnt[c0] = (int)(run & 0xffffu);
        if (c0 + 1 < n) cnt[c0 + 1] = (int)(run >> 16);
    }
    __syncthreads();
    for (int r = t >> 6; r < NHB; r += 4)
        if (jc < pc) __builtin_nontemporal_store(tile[r][c], &histg[(size_t)r * pc + jc]);
}

// Pass 3: replay the chunk with LDS atomics starting from the scanned bases;
// rank is globally unique -> atomic-free global scatter.
__global__ __launch_bounds__(1024) void scatter_fill(const int* __restrict__ row32,
                                                     const int* __restrict__ col32,
                                                     const unsigned* __restrict__ histg,
                                                     const int* __restrict__ off,
                                                     int* __restrict__ csr,
                                                     int e, int epb, int pc) {
    __shared__ unsigned h[PCAP];
    const int t = threadIdx.x;
    const int b = blockIdx.x;
    const unsigned* src = histg + (size_t)b * pc;
    for (int j = t; j < pc; j += 1024) h[j] = src[j];
    __syncthreads();
    const int base = b * epb;
    const int end = min(e, base + epb);
    for (int i = base + t; i < end; i += 1024) {
        int r = row32[i];
        int c = col32[i];
        unsigned old = atomicAdd(&h[c >> 1], (c & 1) ? 0x10000u : 1u);
        unsigned rank = (c & 1) ? (old >> 16) : (old & 0xffffu);
        csr[off[c] + (int)rank] = r;
    }
}

// ---- fallback (N > 2*PCAP or huge E): single-atomic-pass path ----
__global__ void convert_count(const void* __restrict__ ei,
                              int* __restrict__ row32, int* __restrict__ col32,
                              int* __restrict__ rank32,
                              int* __restrict__ cnt,
                              const int* __restrict__ flags, int e) {
    int i = blockIdx.x * 256 + threadIdx.x;
    if (i < e) {
        const bool i64 = flags[1] != 0;
        int r = edge_at(ei, i, i64);
        int c = edge_at(ei, (long long)e + i, i64);
        row32[i] = r;
        col32[i] = c;
        rank32[i] = atomicAdd(&cnt[c], 1);
    }
}

__global__ void fill_csr(const int* __restrict__ row32, const int* __restrict__ col32,
                         const int* __restrict__ rank32, const int* __restrict__ off,
                         int* __restrict__ csr_src, int e) {
    int i = blockIdx.x * 256 + threadIdx.x;
    if (i < e) {
        csr_src[off[col32[i]] + rank32[i]] = row32[i];
    }
}

__global__ __launch_bounds__(256) void deg_reduce(const int* __restrict__ cnt,
                                                  int* __restrict__ bsum, int n) {
    __shared__ int sm[4];
    const int t = threadIdx.x;
    int i = blockIdx.x * 256 + t;
    int v = (i < n) ? cnt[i] : 0;
#pragma unroll
    for (int d = 32; d >= 1; d >>= 1) v += __shfl_down(v, d);
    if ((t & 63) == 0) sm[t >> 6] = v;
    __syncthreads();
    if (t == 0) bsum[blockIdx.x] = sm[0] + sm[1] + sm[2] + sm[3];
}

__global__ __launch_bounds__(256) void scan_bsums(int* __restrict__ bsum, int nb) {
    __shared__ int sm[256];
    const int t = threadIdx.x;
    sm[t] = (t < nb) ? bsum[t] : 0;
    __syncthreads();
#pragma unroll
    for (int d = 1; d < 256; d <<= 1) {
        int v = (t >= d) ? sm[t - d] : 0;
        __syncthreads();
        sm[t] += v;
        __syncthreads();
    }
    if (t < nb) bsum[t] = (t == 0) ? 0 : sm[t - 1];
}

__global__ __launch_bounds__(256) void write_off(const int* __restrict__ cnt,
                                                 const int* __restrict__ bsum,
                                                 int* __restrict__ off,
                                                 float* __restrict__ dinv,
                                                 int n, int e_total) {
    __shared__ int sm[256];
    const int t = threadIdx.x;
    const int i = blockIdx.x * 256 + t;
    const int c = (i < n) ? cnt[i] : 0;
    sm[t] = c;
    __syncthreads();
#pragma unroll
    for (int d = 1; d < 256; d <<= 1) {
        int v = (t >= d) ? sm[t - d] : 0;
        __syncthreads();
        sm[t] += v;
        __syncthreads();
    }
    if (i < n) {
        int o = bsum[blockIdx.x] + sm[t] - c;
        off[i] = o;
        dinv[i] = rsqrtf((float)(c + 1));
        if (i == n - 1) off[n] = e_total;
    }
}

// ---------------- unified MFMA GEMM (bf16 compute) ----------------
// G[row][c] = bf16( dinv[row] * sum_k X[row][k]*W[k][c] ).
// Block 256 thr / 4 waves / 64 rows. A=W^T tile (LDS), B=X row fragment.
// D: col(lane&15)=X-row, row(quad*4+reg)=out channel -> packed 8B stores.
template <int COUT, bool XDYN>
__global__ __launch_bounds__(256) void gemm_mfma(const void* __restrict__ Xv,
                                                 const void* __restrict__ Wv,
                                                 const float* __restrict__ dinv,
                                                 unsigned short* __restrict__ G,
                                                 const int* __restrict__ flags, int n) {
    constexpr int WS = 132;  // 66-dword stride: 2-way bank alias = free
    __shared__ __align__(16) short Wt[COUT * WS];
    const int t = threadIdx.x;
    const bool f32 = flags[0] != 0;

    if (f32) {
        const float* W = (const float*)Wv;
        for (int i = t; i < 128 * COUT; i += 256) {
            int k = i / COUT, c = i % COUT;
            Wt[c * WS + k] = (short)f2bfu(W[i]);
        }
    } else {
        const short* W = (const short*)Wv;
        for (int i = t; i < 128 * COUT; i += 256) {
            int k = i / COUT, c = i % COUT;
            Wt[c * WS + k] = W[i];
        }
    }
    __syncthreads();

    const int w = t >> 6, l = t & 63;
    const int m = l & 15, q = l >> 4;
    const int row = blockIdx.x * 64 + w * 16 + m;
    const int xrow = min(row, n - 1);

    bf8v xf[4];
    if (XDYN && f32) {
        const float* X = (const float*)Xv;
#pragma unroll
        for (int ks = 0; ks < 4; ++ks) {
            const float4 a = *(const float4*)&X[(size_t)xrow * 128 + ks * 32 + q * 8];
            const float4 b = *(const float4*)&X[(size_t)xrow * 128 + ks * 32 + q * 8 + 4];
            bf8v v;
            v[0] = (short)f2bfu(a.x); v[1] = (short)f2bfu(a.y);
            v[2] = (short)f2bfu(a.z); v[3] = (short)f2bfu(a.w);
            v[4] = (short)f2bfu(b.x); v[5] = (short)f2bfu(b.y);
            v[6] = (short)f2bfu(b.z); v[7] = (short)f2bfu(b.w);
            xf[ks] = v;
        }
    } else {
        const short* X = (const short*)Xv;
#pragma unroll
        for (int ks = 0; ks < 4; ++ks)
            xf[ks] = *(const bf8v*)&X[(size_t)xrow * 128 + ks * 32 + q * 8];
    }
    const float dv = dinv[xrow];

#pragma unroll
    for (int ct = 0; ct < COUT / 16; ++ct) {
        f4v acc = {0.f, 0.f, 0.f, 0.f};
#pragma unroll
        for (int ks = 0; ks < 4; ++ks) {
            bf8v wf = *(const bf8v*)&Wt[(ct * 16 + m) * WS + ks * 32 + q * 8];
            acc = __builtin_amdgcn_mfma_f32_16x16x32_bf16(wf, xf[ks], acc, 0, 0, 0);
        }
        if (row < n) {
            vu2 u;
            u.x = (unsigned)f2bfu(dv * acc[0]) | ((unsigned)f2bfu(dv * acc[1]) << 16);
            u.y = (unsigned)f2bfu(dv * acc[2]) | ((unsigned)f2bfu(dv * acc[3]) << 16);
            *(vu2*)&G[(size_t)row * COUT + ct * 16 + q * 4] = u;
        }
    }
}

// One wave per destination node; G bf16; quarter-wave gather (LPG lanes x 16B
// per row). 4-deep unrolled gather: 4*GROUPS edges issue their loads in one
// burst before any FMA consumes them (latency hiding — mean degree 16 fits
// in a single burst for CPL=2). Self row masked to group 0.
template <int CPL, bool RELU, bool WWS, bool WOUT>
__global__ __launch_bounds__(256) void aggregate(const unsigned* __restrict__ Gd,
                                                 const int* __restrict__ off,
                                                 const int* __restrict__ csr_src,
                                                 const float* __restrict__ dinv,
                                                 const void* __restrict__ bias,
                                                 unsigned* __restrict__ Hws,
                                                 void* __restrict__ outp,
                                                 long long out_off,
                                                 const int* __restrict__ flags, int n) {
    const int gw = (int)((blockIdx.x * 256u + threadIdx.x) >> 6);
    const int lane = threadIdx.x & 63;
    if (gw >= n) return;
    constexpr int C = CPL * 64;
    constexpr int LPG = (CPL == 2) ? 16 : 8;
    constexpr int GROUPS = 64 / LPG;
    constexpr int RD = C / 2;
    const int g = lane / LPG;
    const int li = lane % LPG;
    const int e0 = off[gw];
    const int e1 = off[gw + 1];
    const float d = dinv[gw];
    const unsigned* __restrict__ Gp = Gd + li * 4;

    float acc[8];
    {
        uint4 sv = *(const uint4*)&Gp[(size_t)gw * RD];
        const float ms = (g == 0) ? 1.f : 0.f;
        acc[0] = ms * bflo(sv.x); acc[1] = ms * bfhi(sv.x);
        acc[2] = ms * bflo(sv.y); acc[3] = ms * bfhi(sv.y);
        acc[4] = ms * bflo(sv.z); acc[5] = ms * bfhi(sv.z);
        acc[6] = ms * bflo(sv.w); acc[7] = ms * bfhi(sv.w);
    }

    for (int bs = e0; bs < e1; bs += 64) {
        const int cnt = min(64, e1 - bs);
        const int myidx = (bs + lane < e1) ? csr_src[bs + lane] : 0;
        for (int j = 0; j < cnt; j += 4 * GROUPS) {
            uint4 v[4];
            float mm[4];
#pragma unroll
            for (int u = 0; u < 4; ++u) {
                const int eb = j + u * GROUPS + g;
                const int jj = min(eb, cnt - 1);
                const int s = __shfl(myidx, jj);
                mm[u] = (eb < cnt) ? 1.f : 0.f;
                v[u] = *(const uint4*)&Gp[(size_t)s * RD];
            }
#pragma unroll
            for (int u = 0; u < 4; ++u) {
                acc[0] = fmaf(mm[u], bflo(v[u].x), acc[0]);
                acc[1] = fmaf(mm[u], bfhi(v[u].x), acc[1]);
                acc[2] = fmaf(mm[u], bflo(v[u].y), acc[2]);
                acc[3] = fmaf(mm[u], bfhi(v[u].y), acc[3]);
                acc[4] = fmaf(mm[u], bflo(v[u].z), acc[4]);
                acc[5] = fmaf(mm[u], bfhi(v[u].z), acc[5]);
                acc[6] = fmaf(mm[u], bflo(v[u].w), acc[6]);
                acc[7] = fmaf(mm[u], bfhi(v[u].w), acc[7]);
            }
        }
    }

#pragma unroll
    for (int mask = LPG; mask <= 32; mask <<= 1)
#pragma unroll
        for (int i = 0; i < 8; ++i) acc[i] += __shfl_xor(acc[i], mask);

    const bool f32 = flags[0] != 0;
    float bvf[8];
    if (f32) {
        const float* B = (const float*)bias;
        const float4 b0 = *(const float4*)&B[li * 8];
        const float4 b1 = *(const float4*)&B[li * 8 + 4];
        bvf[0] = b0.x; bvf[1] = b0.y; bvf[2] = b0.z; bvf[3] = b0.w;
        bvf[4] = b1.x; bvf[5] = b1.y; bvf[6] = b1.z; bvf[7] = b1.w;
    } else {
        const uint4 bv = *(const uint4*)&((const unsigned*)bias)[li * 4];
        bvf[0] = bflo(bv.x); bvf[1] = bfhi(bv.x);
        bvf[2] = bflo(bv.y); bvf[3] = bfhi(bv.y);
        bvf[4] = bflo(bv.z); bvf[5] = bfhi(bv.z);
        bvf[6] = bflo(bv.w); bvf[7] = bfhi(bv.w);
    }
    float o[8];
#pragma unroll
    for (int i = 0; i < 8; ++i) {
        o[i] = d * acc[i] + bvf[i];
        if (RELU) o[i] = fmaxf(o[i], 0.f);
    }

    if (g == 0) {
        if constexpr (WWS) {
            vu4 u;
            u.x = (unsigned)f2bfu(o[0]) | ((unsigned)f2bfu(o[1]) << 16);
            u.y = (unsigned)f2bfu(o[2]) | ((unsigned)f2bfu(o[3]) << 16);
            u.z = (unsigned)f2bfu(o[4]) | ((unsigned)f2bfu(o[5]) << 16);
            u.w = (unsigned)f2bfu(o[6]) | ((unsigned)f2bfu(o[7]) << 16);
            unsigned* hb = Hws + (size_t)gw * RD + li * 4;
            __builtin_nontemporal_store(u, (vu4*)hb);
        }
        if constexpr (WOUT) {
            if (f32) {
                float* po = (float*)outp + out_off + (size_t)gw * C + li * 8;
                vf4 w0 = {o[0], o[1], o[2], o[3]};
                vf4 w1 = {o[4], o[5], o[6], o[7]};
                __builtin_nontemporal_store(w0, (vf4*)po);
                __builtin_nontemporal_store(w1, (vf4*)po + 1);
            } else {
                vu4 u;
                u.x = (unsigned)f2bfu(o[0]) | ((unsigned)f2bfu(o[1]) << 16);
                u.y = (unsigned)f2bfu(o[2]) | ((unsigned)f2bfu(o[3]) << 16);
                u.z = (unsigned)f2bfu(o[4]) | ((unsigned)f2bfu(o[5]) << 16);
                u.w = (unsigned)f2bfu(o[6]) | ((unsigned)f2bfu(o[7]) << 16);
                unsigned* ob = (unsigned*)outp + (out_off >> 1) + (size_t)gw * RD + li * 4;
                __builtin_nontemporal_store(u, (vu4*)ob);
            }
        }
    }
}

extern "C" void kernel_launch(void* const* d_in, const int* in_sizes, int n_in,
                              void* d_out, int out_size, void* d_ws, size_t ws_size,
                              hipStream_t stream) {
    const void* x  = d_in[0];
    const void* ei = d_in[1];
    const void* W1 = d_in[2];
    const void* b1 = d_in[3];
    const void* W2 = d_in[4];
    const void* b2 = d_in[5];
    const void* W3 = d_in[6];
    const void* b3 = d_in[7];

    const int N = in_sizes[0] / 128;  // 50000
    const int E = in_sizes[1] / 2;    // 800000

    char* p = (char*)d_ws;
    auto take = [&](size_t bytes) {
        char* q = p;
        p += (bytes + 255) & ~(size_t)255;
        return q;
    };
    const int pc  = (N + 1) / 2;
    const int epb = (E + NHB - 1) / NHB;
    const bool histpath = (pc <= PCAP) && (epb < 65536);

    int*      flags = (int*)take(64);
    int*      cnt   = (int*)take((size_t)N * 4);
    int*      bsum  = (int*)take(1024);
    int*      off   = (int*)take((size_t)(N + 1) * 4);
    float*    dinv  = (float*)take((size_t)N * 4);
    int*      row32 = (int*)take((size_t)E * 4);
    int*      col32 = (int*)take((size_t)E * 4);
    int*      csr   = (int*)take((size_t)E * 4);
    unsigned* histg = (unsigned*)take(histpath ? (size_t)NHB * pc * 4 : 0);
    int*      rank32 = (int*)take(histpath ? 0 : (size_t)E * 4);
    unsigned short* bufA = (unsigned short*)take((size_t)N * 128 * 2);  // G bf16
    unsigned short* bufB = (unsigned short*)take((size_t)N * 128 * 2);  // H bf16
    (void)n_in; (void)out_size; (void)ws_size;

    const int nb = (N + 255) / 256;  // <= 256
    const int eb = (E + 255) / 256;

    detect_dtypes<<<1, 128, 0, stream>>>(x, ei, flags);

    if (histpath) {
        // zero-global-atomic CSR build (round-2 proven config)
        hist_count<<<NHB, 1024, 0, stream>>>(ei, row32, col32, histg, flags, E, epb, pc);
        hist_scan<<<(pc + 63) / 64, 256, 0, stream>>>(histg, cnt, pc, N);
        deg_reduce<<<nb, 256, 0, stream>>>(cnt, bsum, N);
        scan_bsums<<<1, 256, 0, stream>>>(bsum, nb);
        write_off<<<nb, 256, 0, stream>>>(cnt, bsum, off, dinv, N, E);
        scatter_fill<<<NHB, 1024, 0, stream>>>(row32, col32, histg, off, csr, E, epb, pc);
    } else {
        // fallback: single-atomic-pass path
        hipMemsetAsync(cnt, 0, (size_t)N * 4, stream);
        convert_count<<<eb, 256, 0, stream>>>(ei, row32, col32, rank32, cnt, flags, E);
        deg_reduce<<<nb, 256, 0, stream>>>(cnt, bsum, N);
        scan_bsums<<<1, 256, 0, stream>>>(bsum, nb);
        write_off<<<nb, 256, 0, stream>>>(cnt, bsum, off, dinv, N, E);
        fill_csr<<<eb, 256, 0, stream>>>(row32, col32, rank32, off, csr, E);
    }

    const int gb = (N + 63) / 64;  // 782
    const int ab = (N + 3) / 4;    // 12500

    // Layer 1: G = dinv*(x@W1); h1 = relu(dinv*agg + b1) -> bufB (bf16)
    gemm_mfma<128, true><<<gb, 256, 0, stream>>>(x, W1, dinv, bufA, flags, N);
    aggregate<2, true, true, false><<<ab, 256, 0, stream>>>((const unsigned*)bufA, off, csr, dinv, b1, (unsigned*)bufB, nullptr, 0, flags, N);
    // Layer 2: h2 -> bufB (bf16, feeds layer 3) AND d_out[0 : N*128]
    gemm_mfma<128, false><<<gb, 256, 0, stream>>>(bufB, W2, dinv, bufA, flags, N);
    aggregate<2, true, true, true><<<ab, 256, 0, stream>>>((const unsigned*)bufA, off, csr, dinv, b2, (unsigned*)bufB, d_out, 0, flags, N);
    // Layer 3: 64 classes, no relu -> d_out[N*128 : N*192]
    gemm_mfma<64, false><<<gb, 256, 0, stream>>>(bufB, W3, dinv, bufA, flags, N);
    aggregate<1, false, false, true><<<ab, 256, 0, stream>>>((const unsigned*)bufA, off, csr, dinv, b3, nullptr, d_out, (long long)N * 128, flags, N);
}

// Round 6
// 268.235 us; speedup vs baseline: 1.0480x; 1.0480x over previous
//
#include <hip/hip_runtime.h>
#include <hip/hip_bf16.h>

// GCN 3-layer forward on gfx950.
// Established: inputs f32 (flags[0]=1) / edges int64 (flags[1]=1), device-
// detected; bf16 MFMA GEMM (operand-swapped 16x16x32); quarter-wave 2-deep
// gather aggregate (4-deep measured -10us, reverted); zero-global-atomic CSR
// build, NHB=256 (round-2 config, best measured). Round-5 measurement:
// hist_scan was 42.8us @ 1 TB/s, occupancy 12% — 65KB LDS tile (1-2 blk/CU)
// + 64/256 threads in a 256-deep serial scan. This round: hist_scan only is
// rewritten — 32 cols x 256 rows tiles (34.8KB LDS -> 4 blk/CU, grid 782),
// hierarchical scan (8 thr/col x 32 rows, all 256 threads active, serial
// depth ~40). Everything else byte-identical to round 2.

typedef float vf4 __attribute__((ext_vector_type(4)));
typedef unsigned vu4 __attribute__((ext_vector_type(4)));
typedef unsigned vu2 __attribute__((ext_vector_type(2)));
typedef short bf8v __attribute__((ext_vector_type(8)));
typedef float f4v __attribute__((ext_vector_type(4)));

constexpr int PCAP  = 25000;  // packed (2-col) LDS histogram capacity -> N <= 50000
constexpr int NHB   = 256;    // histogram blocks (full chip); epb must stay < 2^16
constexpr int SCOLS = 32;     // packed cols per hist_scan block

__device__ __forceinline__ float bits2f(unsigned u) {
    union { unsigned u; float f; } c; c.u = u; return c.f;
}
__device__ __forceinline__ unsigned short f2bfu(float v) {
    __hip_bfloat16 h = __float2bfloat16(v);
    union { __hip_bfloat16 h; unsigned short u; } c; c.h = h; return c.u;
}
__device__ __forceinline__ float bflo(unsigned d) { return bits2f(d << 16); }
__device__ __forceinline__ float bfhi(unsigned d) { return bits2f(d & 0xffff0000u); }

__global__ void detect_dtypes(const void* __restrict__ x,
                              const void* __restrict__ ei,
                              int* __restrict__ flags) {
    const int t = threadIdx.x;
    const int lane = t & 63;
    if (t < 64) {
        const unsigned short* p = (const unsigned short*)x;
        int e = (p[2 * (lane * 16)] >> 7) & 0xFF;
        unsigned long long m = __ballot(e < 100 || e > 140);
        if (lane == 0) flags[0] = (__popcll(m) > 16) ? 1 : 0;
    } else if (t < 128) {
        const int* p = (const int*)ei;
        unsigned long long m = __ballot(p[2 * (lane * 16) + 1] != 0);
        if (lane == 0) flags[1] = (__popcll(m) < 2) ? 1 : 0;
    }
}

__device__ __forceinline__ int edge_at(const void* ei, long long idx, bool i64) {
    return i64 ? (int)((const long long*)ei)[idx] : ((const int*)ei)[idx];
}

// ---- histogram CSR build (no global atomics) ----
// Pass 1: per-block LDS histogram of a contiguous edge chunk; edges converted
// to int32 on the way. Packed ushort pair per u32; per-block per-col count
// <= epb < 2^16 so the +1 / +(1<<16) LDS atomic can never carry.
__global__ __launch_bounds__(1024) void hist_count(const void* __restrict__ ei,
                                                   int* __restrict__ row32,
                                                   int* __restrict__ col32,
                                                   unsigned* __restrict__ histg,
                                                   const int* __restrict__ flags,
                                                   int e, int epb, int pc) {
    __shared__ unsigned h[PCAP];
    const int t = threadIdx.x;
    const int b = blockIdx.x;
    for (int j = t; j < pc; j += 1024) h[j] = 0u;
    __syncthreads();
    const bool i64 = flags[1] != 0;
    const int base = b * epb;
    const int end = min(e, base + epb);
    for (int i = base + t; i < end; i += 1024) {
        int r = edge_at(ei, i, i64);
        int c = edge_at(ei, (long long)e + i, i64);
        row32[i] = r;
        col32[i] = c;
        atomicAdd(&h[c >> 1], (c & 1) ? 0x10000u : 1u);
    }
    __syncthreads();
    unsigned* out = histg + (size_t)b * pc;
    for (int j = t; j < pc; j += 1024) __builtin_nontemporal_store(h[j], &out[j]);
}

// Pass 2 (rewritten): exclusive prefix over the NHB block rows per packed
// column. 32 cols x 256 rows per block in LDS (34.8KB -> 4 blk/CU, grid 782).
// Hierarchical: 8 threads/col each sum 32 rows (all 256 threads active),
// 8-deep per-col segment scan, then exclusive add-back in place.
// Packed u32 adds are carry-free (per-col totals = degree << 2^16).
__global__ __launch_bounds__(256) void hist_scan(unsigned* __restrict__ histg,
                                                 int* __restrict__ cnt, int pc, int n) {
    __shared__ unsigned tile[NHB][SCOLS + 1];
    __shared__ unsigned segsum[8][SCOLS + 1];
    const int t = threadIdx.x;
    const int jc0 = blockIdx.x * SCOLS;
    for (int idx = t; idx < NHB * SCOLS; idx += 256) {
        int r = idx >> 5, c = idx & 31;
        int jc = jc0 + c;
        tile[r][c] = (jc < pc) ? histg[(size_t)r * pc + jc] : 0u;
    }
    __syncthreads();
    const int c = t & 31, s = t >> 5;
    {
        unsigned run = 0;
#pragma unroll
        for (int k = 0; k < 32; ++k) run += tile[s * 32 + k][c];
        segsum[s][c] = run;
    }
    __syncthreads();
    if (t < 32) {
        unsigned run = 0;
#pragma unroll
        for (int sg = 0; sg < 8; ++sg) {
            unsigned v = segsum[sg][t];
            segsum[sg][t] = run;
            run += v;
        }
        int c0 = (jc0 + t) * 2;
        if (c0 < n) cnt[c0] = (int)(run & 0xffffu);
        if (c0 + 1 < n) cnt[c0 + 1] = (int)(run >> 16);
    }
    __syncthreads();
    {
        unsigned run = segsum[s][c];
#pragma unroll
        for (int k = 0; k < 32; ++k) {
            unsigned v = tile[s * 32 + k][c];
            tile[s * 32 + k][c] = run;
            run += v;
        }
    }
    __syncthreads();
    for (int idx = t; idx < NHB * SCOLS; idx += 256) {
        int r = idx >> 5, c2 = idx & 31;
        int jc = jc0 + c2;
        if (jc < pc) __builtin_nontemporal_store(tile[r][c2], &histg[(size_t)r * pc + jc]);
    }
}

// Pass 3: replay the chunk with LDS atomics starting from the scanned bases;
// rank is globally unique -> atomic-free global scatter.
__global__ __launch_bounds__(1024) void scatter_fill(const int* __restrict__ row32,
                                                     const int* __restrict__ col32,
                                                     const unsigned* __restrict__ histg,
                                                     const int* __restrict__ off,
                                                     int* __restrict__ csr,
                                                     int e, int epb, int pc) {
    __shared__ unsigned h[PCAP];
    const int t = threadIdx.x;
    const int b = blockIdx.x;
    const unsigned* src = histg + (size_t)b * pc;
    for (int j = t; j < pc; j += 1024) h[j] = src[j];
    __syncthreads();
    const int base = b * epb;
    const int end = min(e, base + epb);
    for (int i = base + t; i < end; i += 1024) {
        int r = row32[i];
        int c = col32[i];
        unsigned old = atomicAdd(&h[c >> 1], (c & 1) ? 0x10000u : 1u);
        unsigned rank = (c & 1) ? (old >> 16) : (old & 0xffffu);
        csr[off[c] + (int)rank] = r;
    }
}

// ---- fallback (N > 2*PCAP or huge E): single-atomic-pass path ----
__global__ void convert_count(const void* __restrict__ ei,
                              int* __restrict__ row32, int* __restrict__ col32,
                              int* __restrict__ rank32,
                              int* __restrict__ cnt,
                              const int* __restrict__ flags, int e) {
    int i = blockIdx.x * 256 + threadIdx.x;
    if (i < e) {
        const bool i64 = flags[1] != 0;
        int r = edge_at(ei, i, i64);
        int c = edge_at(ei, (long long)e + i, i64);
        row32[i] = r;
        col32[i] = c;
        rank32[i] = atomicAdd(&cnt[c], 1);
    }
}

__global__ void fill_csr(const int* __restrict__ row32, const int* __restrict__ col32,
                         const int* __restrict__ rank32, const int* __restrict__ off,
                         int* __restrict__ csr_src, int e) {
    int i = blockIdx.x * 256 + threadIdx.x;
    if (i < e) {
        csr_src[off[col32[i]] + rank32[i]] = row32[i];
    }
}

__global__ __launch_bounds__(256) void deg_reduce(const int* __restrict__ cnt,
                                                  int* __restrict__ bsum, int n) {
    __shared__ int sm[4];
    const int t = threadIdx.x;
    int i = blockIdx.x * 256 + t;
    int v = (i < n) ? cnt[i] : 0;
#pragma unroll
    for (int d = 32; d >= 1; d >>= 1) v += __shfl_down(v, d);
    if ((t & 63) == 0) sm[t >> 6] = v;
    __syncthreads();
    if (t == 0) bsum[blockIdx.x] = sm[0] + sm[1] + sm[2] + sm[3];
}

__global__ __launch_bounds__(256) void scan_bsums(int* __restrict__ bsum, int nb) {
    __shared__ int sm[256];
    const int t = threadIdx.x;
    sm[t] = (t < nb) ? bsum[t] : 0;
    __syncthreads();
#pragma unroll
    for (int d = 1; d < 256; d <<= 1) {
        int v = (t >= d) ? sm[t - d] : 0;
        __syncthreads();
        sm[t] += v;
        __syncthreads();
    }
    if (t < nb) bsum[t] = (t == 0) ? 0 : sm[t - 1];
}

__global__ __launch_bounds__(256) void write_off(const int* __restrict__ cnt,
                                                 const int* __restrict__ bsum,
                                                 int* __restrict__ off,
                                                 float* __restrict__ dinv,
                                                 int n, int e_total) {
    __shared__ int sm[256];
    const int t = threadIdx.x;
    const int i = blockIdx.x * 256 + t;
    const int c = (i < n) ? cnt[i] : 0;
    sm[t] = c;
    __syncthreads();
#pragma unroll
    for (int d = 1; d < 256; d <<= 1) {
        int v = (t >= d) ? sm[t - d] : 0;
        __syncthreads();
        sm[t] += v;
        __syncthreads();
    }
    if (i < n) {
        int o = bsum[blockIdx.x] + sm[t] - c;
        off[i] = o;
        dinv[i] = rsqrtf((float)(c + 1));
        if (i == n - 1) off[n] = e_total;
    }
}

// ---------------- unified MFMA GEMM (bf16 compute) ----------------
// G[row][c] = bf16( dinv[row] * sum_k X[row][k]*W[k][c] ).
// Block 256 thr / 4 waves / 64 rows. A=W^T tile (LDS), B=X row fragment.
// D: col(lane&15)=X-row, row(quad*4+reg)=out channel -> packed 8B stores.
template <int COUT, bool XDYN>
__global__ __launch_bounds__(256) void gemm_mfma(const void* __restrict__ Xv,
                                                 const void* __restrict__ Wv,
                                                 const float* __restrict__ dinv,
                                                 unsigned short* __restrict__ G,
                                                 const int* __restrict__ flags, int n) {
    constexpr int WS = 132;  // 66-dword stride: 2-way bank alias = free
    __shared__ __align__(16) short Wt[COUT * WS];
    const int t = threadIdx.x;
    const bool f32 = flags[0] != 0;

    if (f32) {
        const float* W = (const float*)Wv;
        for (int i = t; i < 128 * COUT; i += 256) {
            int k = i / COUT, c = i % COUT;
            Wt[c * WS + k] = (short)f2bfu(W[i]);
        }
    } else {
        const short* W = (const short*)Wv;
        for (int i = t; i < 128 * COUT; i += 256) {
            int k = i / COUT, c = i % COUT;
            Wt[c * WS + k] = W[i];
        }
    }
    __syncthreads();

    const int w = t >> 6, l = t & 63;
    const int m = l & 15, q = l >> 4;
    const int row = blockIdx.x * 64 + w * 16 + m;
    const int xrow = min(row, n - 1);

    bf8v xf[4];
    if (XDYN && f32) {
        const float* X = (const float*)Xv;
#pragma unroll
        for (int ks = 0; ks < 4; ++ks) {
            const float4 a = *(const float4*)&X[(size_t)xrow * 128 + ks * 32 + q * 8];
            const float4 b = *(const float4*)&X[(size_t)xrow * 128 + ks * 32 + q * 8 + 4];
            bf8v v;
            v[0] = (short)f2bfu(a.x); v[1] = (short)f2bfu(a.y);
            v[2] = (short)f2bfu(a.z); v[3] = (short)f2bfu(a.w);
            v[4] = (short)f2bfu(b.x); v[5] = (short)f2bfu(b.y);
            v[6] = (short)f2bfu(b.z); v[7] = (short)f2bfu(b.w);
            xf[ks] = v;
        }
    } else {
        const short* X = (const short*)Xv;
#pragma unroll
        for (int ks = 0; ks < 4; ++ks)
            xf[ks] = *(const bf8v*)&X[(size_t)xrow * 128 + ks * 32 + q * 8];
    }
    const float dv = dinv[xrow];

#pragma unroll
    for (int ct = 0; ct < COUT / 16; ++ct) {
        f4v acc = {0.f, 0.f, 0.f, 0.f};
#pragma unroll
        for (int ks = 0; ks < 4; ++ks) {
            bf8v wf = *(const bf8v*)&Wt[(ct * 16 + m) * WS + ks * 32 + q * 8];
            acc = __builtin_amdgcn_mfma_f32_16x16x32_bf16(wf, xf[ks], acc, 0, 0, 0);
        }
        if (row < n) {
            vu2 u;
            u.x = (unsigned)f2bfu(dv * acc[0]) | ((unsigned)f2bfu(dv * acc[1]) << 16);
            u.y = (unsigned)f2bfu(dv * acc[2]) | ((unsigned)f2bfu(dv * acc[3]) << 16);
            *(vu2*)&G[(size_t)row * COUT + ct * 16 + q * 4] = u;
        }
    }
}

// One wave per destination node; G bf16; quarter-wave gather (LPG lanes x 16B
// per row, 64/LPG edges per wave-load). Self row masked to group 0.
template <int CPL, bool RELU, bool WWS, bool WOUT>
__global__ __launch_bounds__(256) void aggregate(const unsigned* __restrict__ Gd,
                                                 const int* __restrict__ off,
                                                 const int* __restrict__ csr_src,
                                                 const float* __restrict__ dinv,
                                                 const void* __restrict__ bias,
                                                 unsigned* __restrict__ Hws,
                                                 void* __restrict__ outp,
                                                 long long out_off,
                                                 const int* __restrict__ flags, int n) {
    const int gw = (int)((blockIdx.x * 256u + threadIdx.x) >> 6);
    const int lane = threadIdx.x & 63;
    if (gw >= n) return;
    constexpr int C = CPL * 64;
    constexpr int LPG = (CPL == 2) ? 16 : 8;
    constexpr int GROUPS = 64 / LPG;
    constexpr int RD = C / 2;
    const int g = lane / LPG;
    const int li = lane % LPG;
    const int e0 = off[gw];
    const int e1 = off[gw + 1];
    const float d = dinv[gw];

    float acc[8];
    {
        uint4 sv = *(const uint4*)&Gd[(size_t)gw * RD + li * 4];
        const float ms = (g == 0) ? 1.f : 0.f;
        acc[0] = ms * bflo(sv.x); acc[1] = ms * bfhi(sv.x);
        acc[2] = ms * bflo(sv.y); acc[3] = ms * bfhi(sv.y);
        acc[4] = ms * bflo(sv.z); acc[5] = ms * bfhi(sv.z);
        acc[6] = ms * bflo(sv.w); acc[7] = ms * bfhi(sv.w);
    }

    for (int bs = e0; bs < e1; bs += 64) {
        const int cnt = min(64, e1 - bs);
        const int myidx = (bs + lane < e1) ? csr_src[bs + lane] : 0;
        for (int j = 0; j < cnt; j += 2 * GROUPS) {
#pragma unroll
            for (int u = 0; u < 2; ++u) {
                const int eb = j + u * GROUPS + g;
                const int jj = min(eb, cnt - 1);
                const int s = __shfl(myidx, jj);
                const float m = (eb < cnt) ? 1.f : 0.f;
                uint4 v = *(const uint4*)&Gd[(size_t)s * RD + li * 4];
                acc[0] = fmaf(m, bflo(v.x), acc[0]);
                acc[1] = fmaf(m, bfhi(v.x), acc[1]);
                acc[2] = fmaf(m, bflo(v.y), acc[2]);
                acc[3] = fmaf(m, bfhi(v.y), acc[3]);
                acc[4] = fmaf(m, bflo(v.z), acc[4]);
                acc[5] = fmaf(m, bfhi(v.z), acc[5]);
                acc[6] = fmaf(m, bflo(v.w), acc[6]);
                acc[7] = fmaf(m, bfhi(v.w), acc[7]);
            }
        }
    }

#pragma unroll
    for (int mask = LPG; mask <= 32; mask <<= 1)
#pragma unroll
        for (int i = 0; i < 8; ++i) acc[i] += __shfl_xor(acc[i], mask);

    const bool f32 = flags[0] != 0;
    float bvf[8];
    if (f32) {
        const float* B = (const float*)bias;
        const float4 b0 = *(const float4*)&B[li * 8];
        const float4 b1 = *(const float4*)&B[li * 8 + 4];
        bvf[0] = b0.x; bvf[1] = b0.y; bvf[2] = b0.z; bvf[3] = b0.w;
        bvf[4] = b1.x; bvf[5] = b1.y; bvf[6] = b1.z; bvf[7] = b1.w;
    } else {
        const uint4 bv = *(const uint4*)&((const unsigned*)bias)[li * 4];
        bvf[0] = bflo(bv.x); bvf[1] = bfhi(bv.x);
        bvf[2] = bflo(bv.y); bvf[3] = bfhi(bv.y);
        bvf[4] = bflo(bv.z); bvf[5] = bfhi(bv.z);
        bvf[6] = bflo(bv.w); bvf[7] = bfhi(bv.w);
    }
    float o[8];
#pragma unroll
    for (int i = 0; i < 8; ++i) {
        o[i] = d * acc[i] + bvf[i];
        if (RELU) o[i] = fmaxf(o[i], 0.f);
    }

    if (g == 0) {
        if constexpr (WWS) {
            vu4 u;
            u.x = (unsigned)f2bfu(o[0]) | ((unsigned)f2bfu(o[1]) << 16);
            u.y = (unsigned)f2bfu(o[2]) | ((unsigned)f2bfu(o[3]) << 16);
            u.z = (unsigned)f2bfu(o[4]) | ((unsigned)f2bfu(o[5]) << 16);
            u.w = (unsigned)f2bfu(o[6]) | ((unsigned)f2bfu(o[7]) << 16);
            unsigned* hb = Hws + (size_t)gw * RD + li * 4;
            __builtin_nontemporal_store(u, (vu4*)hb);
        }
        if constexpr (WOUT) {
            if (f32) {
                float* po = (float*)outp + out_off + (size_t)gw * C + li * 8;
                vf4 w0 = {o[0], o[1], o[2], o[3]};
                vf4 w1 = {o[4], o[5], o[6], o[7]};
                __builtin_nontemporal_store(w0, (vf4*)po);
                __builtin_nontemporal_store(w1, (vf4*)po + 1);
            } else {
                vu4 u;
                u.x = (unsigned)f2bfu(o[0]) | ((unsigned)f2bfu(o[1]) << 16);
                u.y = (unsigned)f2bfu(o[2]) | ((unsigned)f2bfu(o[3]) << 16);
                u.z = (unsigned)f2bfu(o[4]) | ((unsigned)f2bfu(o[5]) << 16);
                u.w = (unsigned)f2bfu(o[6]) | ((unsigned)f2bfu(o[7]) << 16);
                unsigned* ob = (unsigned*)outp + (out_off >> 1) + (size_t)gw * RD + li * 4;
                __builtin_nontemporal_store(u, (vu4*)ob);
            }
        }
    }
}

extern "C" void kernel_launch(void* const* d_in, const int* in_sizes, int n_in,
                              void* d_out, int out_size, void* d_ws, size_t ws_size,
                              hipStream_t stream) {
    const void* x  = d_in[0];
    const void* ei = d_in[1];
    const void* W1 = d_in[2];
    const void* b1 = d_in[3];
    const void* W2 = d_in[4];
    const void* b2 = d_in[5];
    const void* W3 = d_in[6];
    const void* b3 = d_in[7];

    const int N = in_sizes[0] / 128;  // 50000
    const int E = in_sizes[1] / 2;    // 800000

    char* p = (char*)d_ws;
    auto take = [&](size_t bytes) {
        char* q = p;
        p += (bytes + 255) & ~(size_t)255;
        return q;
    };
    const int pc  = (N + 1) / 2;
    const int epb = (E + NHB - 1) / NHB;
    const bool histpath = (pc <= PCAP) && (epb < 65536);

    int*      flags = (int*)take(64);
    int*      cnt   = (int*)take((size_t)N * 4);
    int*      bsum  = (int*)take(1024);
    int*      off   = (int*)take((size_t)(N + 1) * 4);
    float*    dinv  = (float*)take((size_t)N * 4);
    int*      row32 = (int*)take((size_t)E * 4);
    int*      col32 = (int*)take((size_t)E * 4);
    int*      csr   = (int*)take((size_t)E * 4);
    unsigned* histg = (unsigned*)take(histpath ? (size_t)NHB * pc * 4 : 0);
    int*      rank32 = (int*)take(histpath ? 0 : (size_t)E * 4);
    unsigned short* bufA = (unsigned short*)take((size_t)N * 128 * 2);  // G bf16
    unsigned short* bufB = (unsigned short*)take((size_t)N * 128 * 2);  // H bf16
    (void)n_in; (void)out_size; (void)ws_size;

    const int nb = (N + 255) / 256;  // <= 256
    const int eb = (E + 255) / 256;

    detect_dtypes<<<1, 128, 0, stream>>>(x, ei, flags);

    if (histpath) {
        // zero-global-atomic CSR build
        hist_count<<<NHB, 1024, 0, stream>>>(ei, row32, col32, histg, flags, E, epb, pc);
        hist_scan<<<(pc + SCOLS - 1) / SCOLS, 256, 0, stream>>>(histg, cnt, pc, N);
        deg_reduce<<<nb, 256, 0, stream>>>(cnt, bsum, N);
        scan_bsums<<<1, 256, 0, stream>>>(bsum, nb);
        write_off<<<nb, 256, 0, stream>>>(cnt, bsum, off, dinv, N, E);
        scatter_fill<<<NHB, 1024, 0, stream>>>(row32, col32, histg, off, csr, E, epb, pc);
    } else {
        // fallback: single-atomic-pass path
        hipMemsetAsync(cnt, 0, (size_t)N * 4, stream);
        convert_count<<<eb, 256, 0, stream>>>(ei, row32, col32, rank32, cnt, flags, E);
        deg_reduce<<<nb, 256, 0, stream>>>(cnt, bsum, N);
        scan_bsums<<<1, 256, 0, stream>>>(bsum, nb);
        write_off<<<nb, 256, 0, stream>>>(cnt, bsum, off, dinv, N, E);
        fill_csr<<<eb, 256, 0, stream>>>(row32, col32, rank32, off, csr, E);
    }

    const int gb = (N + 63) / 64;  // 782
    const int ab = (N + 3) / 4;    // 12500

    // Layer 1: G = dinv*(x@W1); h1 = relu(dinv*agg + b1) -> bufB (bf16)
    gemm_mfma<128, true><<<gb, 256, 0, stream>>>(x, W1, dinv, bufA, flags, N);
    aggregate<2, true, true, false><<<ab, 256, 0, stream>>>((const unsigned*)bufA, off, csr, dinv, b1, (unsigned*)bufB, nullptr, 0, flags, N);
    // Layer 2: h2 -> bufB (bf16, feeds layer 3) AND d_out[0 : N*128]
    gemm_mfma<128, false><<<gb, 256, 0, stream>>>(bufB, W2, dinv, bufA, flags, N);
    aggregate<2, true, true, true><<<ab, 256, 0, stream>>>((const unsigned*)bufA, off, csr, dinv, b2, (unsigned*)bufB, d_out, 0, flags, N);
    // Layer 3: 64 classes, no relu -> d_out[N*128 : N*192]
    gemm_mfma<64, false><<<gb, 256, 0, stream>>>(bufB, W3, dinv, bufA, flags, N);
    aggregate<1, false, false, true><<<ab, 256, 0, stream>>>((const unsigned*)bufA, off, csr, dinv, b3, nullptr, d_out, (long long)N * 128, flags, N);
}